// Round 3
// baseline (322.682 us; speedup 1.0000x reference)
//
#include <hip/hip_runtime.h>

#define Bv 8
#define Cv 256
#define Hv 128
#define Wv 128
#define Kv 7
#define HID 16
#define EPS 1e-5f
#define BCn (Bv * Cv)        // 2048
#define BCHn (BCn * Hv)      // 262144

// ---- intermediates in module-scope device memory: no d_ws dependence ----
__device__ float g_wh[BCHn];     // (B,C,H) strip weight, H-direction
__device__ float g_ww[BCHn];     // (B,C,W) strip weight, W-direction
__device__ float g_gh[BCn];      // gate mean, H-direction
__device__ float g_gw[BCn];      // gate mean, W-direction
__device__ float g_mean[BCn];    // global mean pool (B,C)
__device__ float g_max[BCn];     // global max pool (B,C)
__device__ float g_c0[BCn];      // 1 + beta*ca_w
__device__ float g_cH[BCn];      // alpha*lam_h
__device__ float g_cW[BCn];      // alpha*lam_w

// ---------------------------------------------------------------------------
// Kernel 1: per-(b,c) plane pooling + both strip convs + gate partials.
// Block = 256 threads; each half-wave (32 lanes) reads one 128-float row per
// iter as float4 (16B/lane, fully coalesced). 16 iters cover the plane.
// ---------------------------------------------------------------------------
__global__ __launch_bounds__(256) void fused_pool_dir(
    const float* __restrict__ x,
    const float* __restrict__ hw_sq_w, const float* __restrict__ hw_sq_b,
    const float* __restrict__ hw_conv,
    const float* __restrict__ hw_bn_g, const float* __restrict__ hw_bn_b,
    const float* __restrict__ hw_bn_m, const float* __restrict__ hw_bn_v,
    const float* __restrict__ ww_sq_w, const float* __restrict__ ww_sq_b,
    const float* __restrict__ ww_conv,
    const float* __restrict__ ww_bn_g, const float* __restrict__ ww_bn_b,
    const float* __restrict__ ww_bn_m, const float* __restrict__ ww_bn_v,
    const float* __restrict__ gate_w,
    const float* __restrict__ gg, const float* __restrict__ gb,
    const float* __restrict__ gm, const float* __restrict__ gv)
{
    const int bc   = blockIdx.x;
    const int c    = bc & (Cv - 1);
    const size_t base = (size_t)bc * (Hv * Wv);
    const int tid  = threadIdx.x;
    const int lane = tid & 63;
    const int wv   = tid >> 6;        // wave 0..3
    const int half = lane >> 5;
    const int li   = lane & 31;
    const int w0   = li * 4;
    const int grp  = wv * 2 + half;   // row phase 0..7

    __shared__ float ph_avg[Hv], ph_max[Hv];   // pool over W -> per-h
    __shared__ float pw_avg[Wv], pw_max[Wv];   // pool over H -> per-w
    __shared__ float lsum[8][Wv], lmax[8][Wv];
    __shared__ float sbuf[2][Hv];
    __shared__ float redS[4], redM[4];

    float cs0 = 0.f, cs1 = 0.f, cs2 = 0.f, cs3 = 0.f;
    float cm0 = -INFINITY, cm1 = -INFINITY, cm2 = -INFINITY, cm3 = -INFINITY;

    for (int j = 0; j < Hv / 8; ++j) {
        const int h = grp + 8 * j;
        const float4 u = *reinterpret_cast<const float4*>(x + base + (size_t)h * Wv + w0);
        const float a0 = u.x, a1 = u.y, a2 = u.z, a3 = u.w;
        cs0 += a0; cs1 += a1; cs2 += a2; cs3 += a3;
        cm0 = fmaxf(cm0, a0); cm1 = fmaxf(cm1, a1);
        cm2 = fmaxf(cm2, a2); cm3 = fmaxf(cm3, a3);
        float rs = (a0 + a1) + (a2 + a3);
        float rm = fmaxf(fmaxf(a0, a1), fmaxf(a2, a3));
        #pragma unroll
        for (int off = 16; off > 0; off >>= 1) {
            rs += __shfl_down(rs, off);
            rm = fmaxf(rm, __shfl_down(rm, off));
        }
        if (li == 0) { ph_avg[h] = rs * (1.0f / Wv); ph_max[h] = rm; }
    }
    lsum[grp][w0] = cs0; lsum[grp][w0+1] = cs1; lsum[grp][w0+2] = cs2; lsum[grp][w0+3] = cs3;
    lmax[grp][w0] = cm0; lmax[grp][w0+1] = cm1; lmax[grp][w0+2] = cm2; lmax[grp][w0+3] = cm3;
    __syncthreads();                                        // #1

    float s = 0.f, m = -INFINITY;
    if (tid < Wv) {
        #pragma unroll
        for (int g = 0; g < 8; ++g) { s += lsum[g][tid]; m = fmaxf(m, lmax[g][tid]); }
        pw_avg[tid] = s * (1.0f / Hv);
        pw_max[tid] = m;
    }
    #pragma unroll
    for (int off = 32; off > 0; off >>= 1) {
        s += __shfl_down(s, off);
        m = fmaxf(m, __shfl_down(m, off));
    }
    if (lane == 0) { redS[wv] = s; redM[wv] = m; }
    __syncthreads();                                        // #2
    if (tid == 0) {
        g_mean[bc] = (redS[0] + redS[1] + redS[2] + redS[3]) * (1.0f / (Hv * Wv));
        g_max[bc]  = fmaxf(fmaxf(redM[0], redM[1]), fmaxf(redM[2], redM[3]));
    }

    // ---- direction phase: waves 0-1 => H-dir, waves 2-3 => W-dir ----
    const int dir = tid >> 7;
    const int l   = tid & 127;
    const float* sqw = dir ? ww_sq_w : hw_sq_w;
    const float* sqb = dir ? ww_sq_b : hw_sq_b;
    const float pa = dir ? pw_avg[l] : ph_avg[l];
    const float pm = dir ? pw_max[l] : ph_max[l];
    sbuf[dir][l] = sqw[0] * pm + sqw[1] * pa + sqb[0];
    __syncthreads();                                        // #3

    const float* conv = dir ? ww_conv : hw_conv;
    float y = 0.f;
    #pragma unroll
    for (int d = 0; d < 3; ++d) {
        const int dil = d + 1;
        #pragma unroll
        for (int k = 0; k < Kv; ++k) {
            const int p = l + dil * (k - 3);
            const float sv = (p >= 0 && p < Hv) ? sbuf[dir][p] : 0.f;
            y += sv * conv[(d * Cv + c) * Kv + k];
        }
    }
    const float* bg = dir ? ww_bn_g : hw_bn_g;
    const float* bb = dir ? ww_bn_b : hw_bn_b;
    const float* bm = dir ? ww_bn_m : hw_bn_m;
    const float* bv = dir ? ww_bn_v : hw_bn_v;
    const float sc  = bg[c] * rsqrtf(bv[c] + EPS);
    const float yb  = (y - bm[c]) * sc + bb[c];
    const float wgt = 1.f / (1.f + expf(-yb));
    (dir ? g_ww : g_wh)[(size_t)bc * Hv + l] = wgt;

    const float gsc = gg[c] * rsqrtf(gv[c] + EPS);
    float gy = fmaxf((wgt * gate_w[c] - gm[c]) * gsc + gb[c], 0.f);
    #pragma unroll
    for (int off = 32; off > 0; off >>= 1) gy += __shfl_down(gy, off);
    if (lane == 0) redS[wv] = gy;   // safe: all pre-#3 reads of redS completed
    __syncthreads();                                        // #4
    if (tid == 0) {
        g_gh[bc] = (redS[0] + redS[1]) * (1.0f / Hv);
        g_gw[bc] = (redS[2] + redS[3]) * (1.0f / Wv);
    }
}

// ---------------------------------------------------------------------------
// Kernel 2: per-batch channel-attention MLP + orientation softmax mix.
// Grid = B blocks, 256 threads (one per channel).
// ---------------------------------------------------------------------------
__global__ __launch_bounds__(256) void mix_ca_kernel(
    const float* __restrict__ mix_W, const float* __restrict__ mix_b,
    const float* __restrict__ fc1,   // (HID, C)
    const float* __restrict__ fc2,   // (C, HID)
    const float* __restrict__ alpha_p, const float* __restrict__ beta_p)
{
    const int b = blockIdx.x;
    const int c = threadIdx.x;
    const int bc = b * Cv + c;
    __shared__ float vmean[Cv], vmax[Cv], hm[HID], hx[HID];

    vmean[c] = g_mean[bc];
    vmax[c]  = g_max[bc];
    __syncthreads();

    if (c < HID) {
        float am = 0.f, ax = 0.f;
        for (int j = 0; j < Cv; ++j) {
            const float f = fc1[c * Cv + j];
            am += vmean[j] * f;
            ax += vmax[j] * f;
        }
        hm[c] = fmaxf(am, 0.f);
        hx[c] = fmaxf(ax, 0.f);
    }
    __syncthreads();

    float om = 0.f, ox = 0.f;
    #pragma unroll
    for (int h = 0; h < HID; ++h) {
        const float f = fc2[c * HID + h];
        om += hm[h] * f;
        ox += hx[h] * f;
    }
    const float caw = 1.f / (1.f + expf(-(om + ox)));

    const float ghv = g_gh[bc], gwv = g_gw[bc];
    const float z0 = ghv * mix_W[0] + gwv * mix_W[1] + mix_b[0];
    const float z1 = ghv * mix_W[2] + gwv * mix_W[3] + mix_b[1];
    const float zm = fmaxf(z0, z1);
    const float e0 = expf(z0 - zm), e1 = expf(z1 - zm);
    const float inv = 1.f / (e0 + e1);

    const float alpha = alpha_p ? alpha_p[0] : 1.0f;
    const float beta  = beta_p  ? beta_p[0]  : 1.0f;
    g_c0[bc] = 1.f + beta * caw;
    g_cH[bc] = alpha * e0 * inv;
    g_cW[bc] = alpha * e1 * inv;
}

// ---------------------------------------------------------------------------
// Kernel 3: fused elementwise apply.
//   out = x * (c0 + cH*w_h[h] + cW*w_w[w])
// ---------------------------------------------------------------------------
__global__ __launch_bounds__(256) void final_kernel(
    const float* __restrict__ x, float* __restrict__ out)
{
    const int bc = blockIdx.x;
    const size_t base = (size_t)bc * (Hv * Wv);
    const int tid  = threadIdx.x;
    const int lane = tid & 63;
    const int wv   = tid >> 6;
    const int half = lane >> 5;
    const int li   = lane & 31;
    const int w0   = li * 4;
    const int grp  = wv * 2 + half;

    __shared__ float cw[Wv];
    const float c0 = g_c0[bc];
    const float cH = g_cH[bc];
    if (tid < Wv) cw[tid] = g_cW[bc] * g_ww[(size_t)bc * Wv + tid];
    __syncthreads();

    const float cwa = cw[w0], cwb = cw[w0+1], cwc = cw[w0+2], cwd = cw[w0+3];

    for (int j = 0; j < Hv / 8; ++j) {
        const int h = grp + 8 * j;
        const float wh = c0 + cH * g_wh[(size_t)bc * Hv + h];
        const size_t off = base + (size_t)h * Wv + w0;
        const float4 u = *reinterpret_cast<const float4*>(x + off);
        float4 r;
        r.x = u.x * (wh + cwa);
        r.y = u.y * (wh + cwb);
        r.z = u.z * (wh + cwc);
        r.w = u.w * (wh + cwd);
        *reinterpret_cast<float4*>(out + off) = r;
    }
}

// ---------------------------------------------------------------------------
extern "C" void kernel_launch(void* const* d_in, const int* in_sizes, int n_in,
                              void* d_out, int out_size, void* d_ws, size_t ws_size,
                              hipStream_t stream)
{
    const float* x       = (const float*)d_in[0];
    const float* hw_sq_w = (const float*)d_in[1];
    const float* hw_sq_b = (const float*)d_in[2];
    const float* hw_conv = (const float*)d_in[3];
    const float* hw_bn_g = (const float*)d_in[4];
    const float* hw_bn_b = (const float*)d_in[5];
    const float* hw_bn_m = (const float*)d_in[6];
    const float* hw_bn_v = (const float*)d_in[7];
    const float* ww_sq_w = (const float*)d_in[8];
    const float* ww_sq_b = (const float*)d_in[9];
    const float* ww_conv = (const float*)d_in[10];
    const float* ww_bn_g = (const float*)d_in[11];
    const float* ww_bn_b = (const float*)d_in[12];
    const float* ww_bn_m = (const float*)d_in[13];
    const float* ww_bn_v = (const float*)d_in[14];
    const float* gate_w  = (const float*)d_in[15];
    const float* g_bn_g  = (const float*)d_in[16];
    const float* g_bn_b  = (const float*)d_in[17];
    const float* g_bn_m  = (const float*)d_in[18];
    const float* g_bn_v  = (const float*)d_in[19];
    const float* mix_W   = (const float*)d_in[20];
    const float* mix_b   = (const float*)d_in[21];
    const float* ca_fc1  = (const float*)d_in[22];
    const float* ca_fc2  = (const float*)d_in[23];
    const float* alpha_p = (n_in > 24) ? (const float*)d_in[24] : nullptr;
    const float* beta_p  = (n_in > 25) ? (const float*)d_in[25] : nullptr;
    float* out = (float*)d_out;
    (void)in_sizes; (void)out_size; (void)d_ws; (void)ws_size;

    fused_pool_dir<<<dim3(BCn), dim3(256), 0, stream>>>(
        x, hw_sq_w, hw_sq_b, hw_conv, hw_bn_g, hw_bn_b, hw_bn_m, hw_bn_v,
        ww_sq_w, ww_sq_b, ww_conv, ww_bn_g, ww_bn_b, ww_bn_m, ww_bn_v,
        gate_w, g_bn_g, g_bn_b, g_bn_m, g_bn_v);

    mix_ca_kernel<<<dim3(Bv), dim3(256), 0, stream>>>(
        mix_W, mix_b, ca_fc1, ca_fc2, alpha_p, beta_p);

    final_kernel<<<dim3(BCn), dim3(256), 0, stream>>>(x, out);
}

// Round 5
// 306.950 us; speedup vs baseline: 1.0513x; 1.0513x over previous
//
#include <hip/hip_runtime.h>

#define Bv 8
#define Cv 256
#define Hv 128
#define Wv 128
#define Kv 7
#define HID 16
#define EPS 1e-5f
#define BCn (Bv * Cv)        // 2048
#define BCHn (BCn * Hv)      // 262144

typedef float vfloat4 __attribute__((ext_vector_type(4)));   // native vec for NT store

// ---- intermediates in module-scope device memory: no d_ws dependence ----
__device__ float g_wh[BCHn];     // (B,C,H) strip weight, H-direction
__device__ float g_ww[BCHn];     // (B,C,W) strip weight, W-direction
__device__ float g_gh[BCn];      // gate mean, H-direction
__device__ float g_gw[BCn];      // gate mean, W-direction
__device__ float g_mean[BCn];    // global mean pool (B,C)
__device__ float g_max[BCn];     // global max pool (B,C)

// ---------------------------------------------------------------------------
// Kernel 1: per-(b,c) plane pooling + both strip convs + gate partials.
// Block = 256 threads; each half-wave (32 lanes) reads one 128-float row per
// iter as float4 (16B/lane, fully coalesced). 16 iters cover the plane.
// ---------------------------------------------------------------------------
__global__ __launch_bounds__(256) void fused_pool_dir(
    const float* __restrict__ x,
    const float* __restrict__ hw_sq_w, const float* __restrict__ hw_sq_b,
    const float* __restrict__ hw_conv,
    const float* __restrict__ hw_bn_g, const float* __restrict__ hw_bn_b,
    const float* __restrict__ hw_bn_m, const float* __restrict__ hw_bn_v,
    const float* __restrict__ ww_sq_w, const float* __restrict__ ww_sq_b,
    const float* __restrict__ ww_conv,
    const float* __restrict__ ww_bn_g, const float* __restrict__ ww_bn_b,
    const float* __restrict__ ww_bn_m, const float* __restrict__ ww_bn_v,
    const float* __restrict__ gate_w,
    const float* __restrict__ gg, const float* __restrict__ gb,
    const float* __restrict__ gm, const float* __restrict__ gv)
{
    const int bc   = blockIdx.x;
    const int c    = bc & (Cv - 1);
    const size_t base = (size_t)bc * (Hv * Wv);
    const int tid  = threadIdx.x;
    const int lane = tid & 63;
    const int wv   = tid >> 6;        // wave 0..3
    const int half = lane >> 5;
    const int li   = lane & 31;
    const int w0   = li * 4;
    const int grp  = wv * 2 + half;   // row phase 0..7

    __shared__ float ph_avg[Hv], ph_max[Hv];   // pool over W -> per-h
    __shared__ float pw_avg[Wv], pw_max[Wv];   // pool over H -> per-w
    __shared__ float lsum[8][Wv], lmax[8][Wv];
    __shared__ float sbuf[2][Hv];
    __shared__ float redS[4], redM[4];

    float cs0 = 0.f, cs1 = 0.f, cs2 = 0.f, cs3 = 0.f;
    float cm0 = -INFINITY, cm1 = -INFINITY, cm2 = -INFINITY, cm3 = -INFINITY;

    #pragma unroll 4
    for (int j = 0; j < Hv / 8; ++j) {
        const int h = grp + 8 * j;
        const float4 u = *reinterpret_cast<const float4*>(x + base + (size_t)h * Wv + w0);
        const float a0 = u.x, a1 = u.y, a2 = u.z, a3 = u.w;
        cs0 += a0; cs1 += a1; cs2 += a2; cs3 += a3;
        cm0 = fmaxf(cm0, a0); cm1 = fmaxf(cm1, a1);
        cm2 = fmaxf(cm2, a2); cm3 = fmaxf(cm3, a3);
        float rs = (a0 + a1) + (a2 + a3);
        float rm = fmaxf(fmaxf(a0, a1), fmaxf(a2, a3));
        #pragma unroll
        for (int off = 16; off > 0; off >>= 1) {
            rs += __shfl_down(rs, off);
            rm = fmaxf(rm, __shfl_down(rm, off));
        }
        if (li == 0) { ph_avg[h] = rs * (1.0f / Wv); ph_max[h] = rm; }
    }
    lsum[grp][w0] = cs0; lsum[grp][w0+1] = cs1; lsum[grp][w0+2] = cs2; lsum[grp][w0+3] = cs3;
    lmax[grp][w0] = cm0; lmax[grp][w0+1] = cm1; lmax[grp][w0+2] = cm2; lmax[grp][w0+3] = cm3;
    __syncthreads();                                        // #1

    float s = 0.f, m = -INFINITY;
    if (tid < Wv) {
        #pragma unroll
        for (int g = 0; g < 8; ++g) { s += lsum[g][tid]; m = fmaxf(m, lmax[g][tid]); }
        pw_avg[tid] = s * (1.0f / Hv);
        pw_max[tid] = m;
    }
    #pragma unroll
    for (int off = 32; off > 0; off >>= 1) {
        s += __shfl_down(s, off);
        m = fmaxf(m, __shfl_down(m, off));
    }
    if (lane == 0) { redS[wv] = s; redM[wv] = m; }
    __syncthreads();                                        // #2
    if (tid == 0) {
        g_mean[bc] = (redS[0] + redS[1] + redS[2] + redS[3]) * (1.0f / (Hv * Wv));
        g_max[bc]  = fmaxf(fmaxf(redM[0], redM[1]), fmaxf(redM[2], redM[3]));
    }

    // ---- direction phase: waves 0-1 => H-dir, waves 2-3 => W-dir ----
    const int dir = tid >> 7;
    const int l   = tid & 127;
    const float* sqw = dir ? ww_sq_w : hw_sq_w;
    const float* sqb = dir ? ww_sq_b : hw_sq_b;
    const float pa = dir ? pw_avg[l] : ph_avg[l];
    const float pm = dir ? pw_max[l] : ph_max[l];
    sbuf[dir][l] = sqw[0] * pm + sqw[1] * pa + sqb[0];
    __syncthreads();                                        // #3

    const float* conv = dir ? ww_conv : hw_conv;
    float y = 0.f;
    #pragma unroll
    for (int d = 0; d < 3; ++d) {
        const int dil = d + 1;
        #pragma unroll
        for (int k = 0; k < Kv; ++k) {
            const int p = l + dil * (k - 3);
            const float sv = (p >= 0 && p < Hv) ? sbuf[dir][p] : 0.f;
            y += sv * conv[(d * Cv + c) * Kv + k];
        }
    }
    const float* bg = dir ? ww_bn_g : hw_bn_g;
    const float* bb = dir ? ww_bn_b : hw_bn_b;
    const float* bm = dir ? ww_bn_m : hw_bn_m;
    const float* bv = dir ? ww_bn_v : hw_bn_v;
    const float sc  = bg[c] * rsqrtf(bv[c] + EPS);
    const float yb  = (y - bm[c]) * sc + bb[c];
    const float wgt = 1.f / (1.f + expf(-yb));
    (dir ? g_ww : g_wh)[(size_t)bc * Hv + l] = wgt;

    const float gsc = gg[c] * rsqrtf(gv[c] + EPS);
    float gy = fmaxf((wgt * gate_w[c] - gm[c]) * gsc + gb[c], 0.f);
    #pragma unroll
    for (int off = 32; off > 0; off >>= 1) gy += __shfl_down(gy, off);
    if (lane == 0) redS[wv] = gy;   // safe: all pre-#3 reads of redS completed
    __syncthreads();                                        // #4
    if (tid == 0) {
        g_gh[bc] = (redS[0] + redS[1]) * (1.0f / Hv);
        g_gw[bc] = (redS[2] + redS[3]) * (1.0f / Wv);
    }
}

// ---------------------------------------------------------------------------
// Kernel 2: fused coefficients + elementwise apply.
// Each block (one (b,c) plane) redundantly computes its batch's channel-
// attention MLP from g_mean/g_max (fc weights are 16 KB, L2-hot), the
// orientation softmax from g_gh/g_gw, then applies:
//   out = x * (c0 + cH*w_h[h] + cW*w_w[w])
// Out stores are non-temporal: out is dead data, don't evict x from L3.
// ---------------------------------------------------------------------------
__global__ __launch_bounds__(256) void final_fused(
    const float* __restrict__ x,
    const float* __restrict__ mix_W, const float* __restrict__ mix_b,
    const float* __restrict__ fc1,   // (HID, C)
    const float* __restrict__ fc2,   // (C, HID)
    const float* __restrict__ alpha_p, const float* __restrict__ beta_p,
    float* __restrict__ out)
{
    const int bc = blockIdx.x;
    const int b  = bc >> 8;
    const int c  = bc & (Cv - 1);
    const size_t base = (size_t)bc * (Hv * Wv);
    const int tid  = threadIdx.x;
    const int lane = tid & 63;
    const int wv   = tid >> 6;
    const int half = lane >> 5;
    const int li   = lane & 31;
    const int w0   = li * 4;
    const int grp  = wv * 2 + half;

    __shared__ float vpool[2][Cv];      // [0]=mean, [1]=max over batch b
    __shared__ float hmx[2][HID];       // [0]=hm (from mean), [1]=hx (from max)
    __shared__ float cw[Wv];
    __shared__ float coef[3];           // c0, cH, cW

    vpool[0][tid] = g_mean[b * Cv + tid];
    vpool[1][tid] = g_max[b * Cv + tid];
    __syncthreads();

    // MLP layer 1: threads 0-127 -> hm, 128-255 -> hx.
    // Within each half: j = (t&127)>>3 selects hidden unit, sub = t&7 gives
    // 8 partials of 32 consecutive channels; reduce via shfl within 8 lanes.
    {
        const int which = tid >> 7;
        const int j   = (tid & 127) >> 3;
        const int sub = tid & 7;
        const float* vs = vpool[which];
        float part = 0.f;
        #pragma unroll 8
        for (int t = 0; t < 32; ++t) {
            const int cc = sub * 32 + t;
            part += vs[cc] * fc1[j * Cv + cc];
        }
        part += __shfl_down(part, 4);
        part += __shfl_down(part, 2);
        part += __shfl_down(part, 1);
        if (sub == 0) hmx[which][j] = fmaxf(part, 0.f);
    }
    __syncthreads();

    if (tid == 0) {
        float om = 0.f, ox = 0.f;
        #pragma unroll
        for (int h = 0; h < HID; ++h) {
            const float f = fc2[c * HID + h];
            om += hmx[0][h] * f;
            ox += hmx[1][h] * f;
        }
        const float caw = 1.f / (1.f + expf(-(om + ox)));

        const float ghv = g_gh[bc], gwv = g_gw[bc];
        const float z0 = ghv * mix_W[0] + gwv * mix_W[1] + mix_b[0];
        const float z1 = ghv * mix_W[2] + gwv * mix_W[3] + mix_b[1];
        const float zm = fmaxf(z0, z1);
        const float e0 = expf(z0 - zm), e1 = expf(z1 - zm);
        const float inv = 1.f / (e0 + e1);

        const float alpha = alpha_p ? alpha_p[0] : 1.0f;
        const float beta  = beta_p  ? beta_p[0]  : 1.0f;
        coef[0] = 1.f + beta * caw;      // c0
        coef[1] = alpha * e0 * inv;      // cH
        coef[2] = alpha * e1 * inv;      // cW
    }
    __syncthreads();

    const float c0 = coef[0];
    const float cH = coef[1];
    if (tid < Wv) cw[tid] = coef[2] * g_ww[(size_t)bc * Wv + tid];
    __syncthreads();

    const float cwa = cw[w0], cwb = cw[w0+1], cwc = cw[w0+2], cwd = cw[w0+3];

    #pragma unroll 4
    for (int j = 0; j < Hv / 8; ++j) {
        const int h = grp + 8 * j;
        const float wh = c0 + cH * g_wh[(size_t)bc * Hv + h];
        const size_t off = base + (size_t)h * Wv + w0;
        const float4 u = *reinterpret_cast<const float4*>(x + off);
        vfloat4 r;
        r.x = u.x * (wh + cwa);
        r.y = u.y * (wh + cwb);
        r.z = u.z * (wh + cwc);
        r.w = u.w * (wh + cwd);
        __builtin_nontemporal_store(r, reinterpret_cast<vfloat4*>(out + off));
    }
}

// ---------------------------------------------------------------------------
extern "C" void kernel_launch(void* const* d_in, const int* in_sizes, int n_in,
                              void* d_out, int out_size, void* d_ws, size_t ws_size,
                              hipStream_t stream)
{
    const float* x       = (const float*)d_in[0];
    const float* hw_sq_w = (const float*)d_in[1];
    const float* hw_sq_b = (const float*)d_in[2];
    const float* hw_conv = (const float*)d_in[3];
    const float* hw_bn_g = (const float*)d_in[4];
    const float* hw_bn_b = (const float*)d_in[5];
    const float* hw_bn_m = (const float*)d_in[6];
    const float* hw_bn_v = (const float*)d_in[7];
    const float* ww_sq_w = (const float*)d_in[8];
    const float* ww_sq_b = (const float*)d_in[9];
    const float* ww_conv = (const float*)d_in[10];
    const float* ww_bn_g = (const float*)d_in[11];
    const float* ww_bn_b = (const float*)d_in[12];
    const float* ww_bn_m = (const float*)d_in[13];
    const float* ww_bn_v = (const float*)d_in[14];
    const float* gate_w  = (const float*)d_in[15];
    const float* g_bn_g  = (const float*)d_in[16];
    const float* g_bn_b  = (const float*)d_in[17];
    const float* g_bn_m  = (const float*)d_in[18];
    const float* g_bn_v  = (const float*)d_in[19];
    const float* mix_W   = (const float*)d_in[20];
    const float* mix_b   = (const float*)d_in[21];
    const float* ca_fc1  = (const float*)d_in[22];
    const float* ca_fc2  = (const float*)d_in[23];
    const float* alpha_p = (n_in > 24) ? (const float*)d_in[24] : nullptr;
    const float* beta_p  = (n_in > 25) ? (const float*)d_in[25] : nullptr;
    float* out = (float*)d_out;
    (void)in_sizes; (void)out_size; (void)d_ws; (void)ws_size;

    fused_pool_dir<<<dim3(BCn), dim3(256), 0, stream>>>(
        x, hw_sq_w, hw_sq_b, hw_conv, hw_bn_g, hw_bn_b, hw_bn_m, hw_bn_v,
        ww_sq_w, ww_sq_b, ww_conv, ww_bn_g, ww_bn_b, ww_bn_m, ww_bn_v,
        gate_w, g_bn_g, g_bn_b, g_bn_m, g_bn_v);

    final_fused<<<dim3(BCn), dim3(256), 0, stream>>>(
        x, mix_W, mix_b, ca_fc1, ca_fc2, alpha_p, beta_p, out);
}